// Round 10
// baseline (381.545 us; speedup 1.0000x reference)
//
#include <hip/hip_runtime.h>

// 3-layer LSTM (B=8192, T=336, F=8, H=20) + FC(20->20 relu) + FC(20->1).
//
// Round 16 = R15 (282us best) + LDS PAD TO 56KB: forbid 3-block/CU residency.
//  Occupancy counter has sat at 14-15% (~4.7 waves/CU) every round — BELOW
//  the 18.75% of uniform 2-block/CU. At 41.5KB, THREE blocks can co-reside
//  (124KB LDS, 9 waves, VGPR ok) -> dispatcher can create {3,..,1} CU
//  imbalance; 3-block CUs set the makespan while 1-block CUs drain early.
//  Padding LDS past 163840/3 (=54.6KB) makes 2 the hard cap -> uniform
//  {2,2}. Code otherwise identical to R15. Clean A/B: if occupancy rises to
//  ~18% and dur drops, the imbalance was real; if all counters unchanged,
//  the structure is at its pacing floor (2 waves/SIMD x 650cy/ts = 182us +
//  unhidable recurrence stall).
//  Kept: PRE/FIN pipeline + swizzle-paired hl (R15), 8 ts/barrier packed
//  rows (R14), prescaled gates + register h_self (R12), hoisted h_in reads
//  + setprio (R11), lgkm-only barrier (R9), XOR swizzle (R9), unit-major
//  leftover tile (R10), LICM pin (R4).
//
// MFMA layouts (m89/m120-verified): A[m][k]: m=lane&15,k=(lane>>4)*8+j;
// B[k][n]: n=lane&15,k=(lane>>4)*8+j; D[m][n]: n=lane&15,m=(lane>>4)*4+reg.

#define T_LEN 336
#define NJ 43   // j=0..43; w0: group j (t=8j..8j+7, j<=41); w1: group j-1; w2: group j-2

typedef _Float16 f16;
typedef _Float16 f16x4 __attribute__((ext_vector_type(4)));
typedef _Float16 f16x8 __attribute__((ext_vector_type(8)));
typedef float f32x4 __attribute__((ext_vector_type(4)));
typedef int i32x2 __attribute__((ext_vector_type(2)));
typedef int i32x4 __attribute__((ext_vector_type(4)));

#define MFMA(a, b, c) __builtin_amdgcn_mfma_f32_16x16x32_f16((a), (b), (c), 0, 0, 0)

// 16B-slot XOR swizzle for 64-f16 (128B) rows
#define SWZ1(n, c) ((c) ^ (((n) & 7) << 3))

#define KS1 1.4426950408889634f   // log2(e)
#define KS2 2.8853900817779268f   // 2*log2(e)

// prescaled activations: y arrives as -KS1*x (sigm) / -KS2*x (tanh)
__device__ __forceinline__ float sigm_p(float y) {
  return __builtin_amdgcn_rcpf(1.0f + __builtin_amdgcn_exp2f(y));
}
__device__ __forceinline__ float tanh_p(float y) {
  return 2.0f * __builtin_amdgcn_rcpf(1.0f + __builtin_amdgcn_exp2f(y)) - 1.0f;
}
__device__ __forceinline__ float tanh_fast(float x) {   // raw arg (cell state)
  return 2.0f * __builtin_amdgcn_rcpf(1.0f + __builtin_amdgcn_exp2f(-KS2 * x)) - 1.0f;
}

// 5 in-lane cells; gate inputs arrive PRESCALED (see gA/gB loaders).
#define CELLS5(DI, DF, DG, DO, DL, HV, HL) {                                                \
  { float i_=sigm_p((DI)[0]), f_=sigm_p((DF)[0]), g_=tanh_p((DG)[0]), o_=sigm_p((DO)[0]);   \
    c0 = f_*c0 + i_*g_; (HV)[0] = (f16)(o_*tanh_fast(c0)); }                                \
  { float i_=sigm_p((DI)[1]), f_=sigm_p((DF)[1]), g_=tanh_p((DG)[1]), o_=sigm_p((DO)[1]);   \
    c1 = f_*c1 + i_*g_; (HV)[1] = (f16)(o_*tanh_fast(c1)); }                                \
  { float i_=sigm_p((DI)[2]), f_=sigm_p((DF)[2]), g_=tanh_p((DG)[2]), o_=sigm_p((DO)[2]);   \
    c2 = f_*c2 + i_*g_; (HV)[2] = (f16)(o_*tanh_fast(c2)); }                                \
  { float i_=sigm_p((DI)[3]), f_=sigm_p((DF)[3]), g_=tanh_p((DG)[3]), o_=sigm_p((DO)[3]);   \
    c3 = f_*c3 + i_*g_; (HV)[3] = (f16)(o_*tanh_fast(c3)); }                                \
  { float i_=sigm_p((DL)[0]), f_=sigm_p((DL)[1]), g_=tanh_p((DL)[2]), o_=sigm_p((DL)[3]);   \
    cL = f_*cL + i_*g_; (HL) = (f16)(o_*tanh_fast(cL)); } }

// PRE phase: 5 independent h_in-chunk MFMAs into named accumulators.
#define PRE5(BA, T0, T1, T2, T3, T4) {                                                      \
  T0 = MFMA(Fa0, (BA), Bi); T1 = MFMA(Fa1, (BA), Bf); T2 = MFMA(Fa2, (BA), Bg);             \
  T3 = MFMA(Fa3, (BA), Bo); T4 = MFMA(Fa4, (BA), BL); }

// bb rebuild from hvS/hlS: 4 hv bperms + swizzle-paired hl (2 bperms).
// lane(n,q) wants bb k=8q..8q+7 of [h_self 20 | pad12]:
//  q0: h0..7; q1: h8..15; q2: h16..19 (+x0-wt garbage); q3: x0-wt garbage.
#define BBGEN(BB) {                                                                         \
  i32x2 _lo = __builtin_bit_cast(i32x2, hvS);                                               \
  int _hlu = (int)(unsigned)__builtin_bit_cast(unsigned short, hlS);                        \
  int _b0 = __builtin_amdgcn_ds_bpermute(adrA, _lo.x);                                      \
  int _b1 = __builtin_amdgcn_ds_bpermute(adrA, _lo.y);                                      \
  int _b2 = __builtin_amdgcn_ds_bpermute(adrB, _lo.x);                                      \
  int _b3 = __builtin_amdgcn_ds_bpermute(adrB, _lo.y);                                      \
  int _sw = __builtin_amdgcn_ds_swizzle(_hlu, 0x401F);  /* lane^16: quad pair */            \
  int _pair = (_hlu & 0xffff) | (_sw << 16);            /* {hl(q), hl(q^1)} */              \
  int _hA = __builtin_amdgcn_ds_bpermute(adr0, _pair);  /* {hl0,hl1} from (n,q0) */         \
  int _hB = __builtin_amdgcn_ds_bpermute(adr2, _pair);  /* {hl2,hl3} from (n,q2) */         \
  int _w0 = (q < 2) ? _b0 : _hA;                                                            \
  int _w1 = (q < 2) ? _b1 : _hB;                                                            \
  i32x4 _bbi = { _w0, _w1, _b2, _b3 };                                                      \
  BB = __builtin_bit_cast(f16x8, _bbi); }

// FIN phase: fold h_self chunk onto PRE accumulators, cells, publish.
#define FIN5(BB, T0, T1, T2, T3, T4, PUB, PC) {                                             \
  f32x4 di = MFMA(Fb0, (BB), T0);                                                           \
  f32x4 df = MFMA(Fb1, (BB), T1);                                                           \
  f32x4 dg = MFMA(Fb2, (BB), T2);                                                           \
  f32x4 dn = MFMA(Fb3, (BB), T3);                                                           \
  f32x4 dl = MFMA(Fb4, (BB), T4);                                                           \
  f16x4 hv; f16 hl; CELLS5(di, df, dg, dn, dl, hv, hl)                                      \
  hvS = hv; hlS = hl;                                                                       \
  f16* dp_ = (PUB);                                                                         \
  if (dp_) { *(f16x4*)&dp_[n * 64 + SWZ1(n, (PC) + q * 4)] = hv;                            \
             dp_[n * 64 + SWZ1(n, (PC) + 16 + q)] = hl; } }

// L0 substep (LDS ring, 2 substeps/row): read row SR col-half SC
// [x(t) 8|h0(t-1) 20|pad4], write h0(t) into row DR col DC+8..27,
// publish into PUBP at col-base PC.
#define L0S(SR, SC, DR, DC, PUBP, PC) {                                                     \
  f16x8 b0 = *(const f16x8*)&zT0[SR][n * 64 + SWZ1(n, (SC) + q * 8)];                       \
  f32x4 di = MFMA(Fa0, b0, Bi), df = MFMA(Fa1, b0, Bf), dg = MFMA(Fa2, b0, Bg),             \
        dn = MFMA(Fa3, b0, Bo), dl = MFMA(Fa4, b0, BL);                                     \
  f16x4 hv; f16 hl; CELLS5(di, df, dg, dn, dl, hv, hl)                                      \
  *(f16x4*)&zT0[DR][n * 64 + SWZ1(n, (DC) + 8 + q * 4)] = hv;                               \
  zT0[DR][n * 64 + SWZ1(n, (DC) + 24 + q)] = hl;                                            \
  f16* dp_ = (PUBP);                                                                        \
  *(f16x4*)&dp_[n * 64 + SWZ1(n, (PC) + q * 4)] = hv;                                       \
  dp_[n * 64 + SWZ1(n, (PC) + 16 + q)] = hl; }

__global__ __launch_bounds__(192, 2) void lstm3_ws_kernel(
    const float* __restrict__ x,
    const float* __restrict__ Wih0, const float* __restrict__ Whh0,
    const float* __restrict__ bih0, const float* __restrict__ bhh0,
    const float* __restrict__ Wih1, const float* __restrict__ Whh1,
    const float* __restrict__ bih1, const float* __restrict__ bhh1,
    const float* __restrict__ Wih2, const float* __restrict__ Whh2,
    const float* __restrict__ bih2, const float* __restrict__ bhh2,
    const float* __restrict__ fc1w, const float* __restrict__ fc1b,
    const float* __restrict__ fc2w, const float* __restrict__ fc2b,
    float* __restrict__ out)
{
  // row r: [x(2r) 8|h0(2r-1) 20|pad4 | x(2r+1) 8|h0(2r) 20|pad4] (swizzled)
  __shared__ __align__(16) f16 zT0[4][1024];
  // [parity][rowset r]: substeps 2r (cols 0..) and 2r+1 (cols 32..)
  __shared__ __align__(16) f16 zT1[2][4][1024];
  __shared__ __align__(16) f16 zT2[2][4][1024];
  __shared__ __align__(16) float pbuf[64];          // fc2 partials
  // residency cap: total LDS ~56KB > 163840/3 -> at most 2 blocks/CU.
  __shared__ __align__(16) f16 cupad[7936];

  const int tid  = threadIdx.x;
  const int w    = tid >> 6;        // wave id = layer id
  const int lane = tid & 63;
  const int n = lane & 15;          // batch elem (N index)
  const int q = lane >> 4;          // quad

  if (blockIdx.x == 0xFFFFFFFFu) cupad[tid] = (f16)1.f;  // keep pad allocated

  // bpermute source-lane byte addresses (lane*4)
  const int adrA = 4 * (n + 32 * (q & 1));
  const int adrB = 4 * (n + 16 + 32 * (q & 1));
  const int adr0 = 4 * n, adr2 = 4 * (n + 32);

  // ---- zero z buffers (h(.)=0, c implicit 0, pads 0) ----
  {
    f16x8 zer;
#pragma unroll
    for (int j = 0; j < 8; ++j) zer[j] = (f16)0.f;
    for (int i = tid; i < 512; i += 192)  ((f16x8*)&zT0[0][0])[i] = zer;
    for (int i = tid; i < 1024; i += 192) ((f16x8*)&zT1[0][0][0])[i] = zer;
    for (int i = tid; i < 1024; i += 192) ((f16x8*)&zT2[0][0][0])[i] = zer;
  }
  __syncthreads();

  // ---- per-wave register-resident fragments (PRESCALED) ----
  auto rowmap = [](int T, int m) { return T < 4 ? T * 20 + m : (m & 3) * 20 + 16 + (m >> 2); };
  auto gscale = [](int T, int m) {
    int g = (T < 4) ? T : (m & 3);
    return (g == 2) ? -KS2 : -KS1;
  };

  f16x8 Fa0{}, Fa1{}, Fa2{}, Fa3{}, Fa4{};   // k-chunk 0 (w0: full [x|h] K)
  f16x8 Fb0{}, Fb1{}, Fb2{}, Fb3{}, Fb4{};   // k-chunk 1 (h_self; unused w0)
  f32x4 Bi{}, Bf{}, Bg{}, Bo{}, BL{};
  float c0 = 0.f, c1 = 0.f, c2 = 0.f, c3 = 0.f, cL = 0.f;
  f16x4 hvS{};                     // register h_self state (w1/w2)
  f16 hlS = (f16)0.f;

  if (w == 0) {
    auto gA0 = [&](int T) {
      int row = rowmap(T, n);
      float sc = gscale(T, n);
      f16x8 r;
#pragma unroll
      for (int j = 0; j < 8; ++j) {
        int k = q * 8 + j;
        float v = (k < 8) ? Wih0[row * 8 + k] : (k < 28 ? Whh0[row * 20 + k - 8] : 0.f);
        r[j] = (f16)(sc * v);
      }
      return r;
    };
    Fa0 = gA0(0); Fa1 = gA0(1); Fa2 = gA0(2); Fa3 = gA0(3); Fa4 = gA0(4);
    auto gB = [&](int T) {
      f32x4 r;
#pragma unroll
      for (int j = 0; j < 4; ++j) {
        int m = q * 4 + j;
        int row = rowmap(T, m);
        r[j] = gscale(T, m) * (bih0[row] + bhh0[row]);
      }
      return r;
    };
    Bi = gB(0); Bf = gB(1); Bg = gB(2); Bo = gB(3); BL = gB(4);
  } else {
    const float* Wi = (w == 1) ? Wih1 : Wih2;
    const float* Wh = (w == 1) ? Whh1 : Whh2;
    const float* bi = (w == 1) ? bih1 : bih2;
    const float* bh = (w == 1) ? bhh1 : bhh2;
    // chunk 0 covers k=0..31 = [h_in 20 | 0 pad]; chunk 1 = [h_self 20 | 0]
    auto gA = [&](int T, int c) {
      int row = rowmap(T, n);
      float sc = gscale(T, n);
      const float* W = c ? Wh : Wi;
      f16x8 r;
#pragma unroll
      for (int j = 0; j < 8; ++j) {
        int k = q * 8 + j;
        r[j] = (f16)((k < 20) ? sc * W[row * 20 + k] : 0.f);
      }
      return r;
    };
    Fa0 = gA(0, 0); Fb0 = gA(0, 1);
    Fa1 = gA(1, 0); Fb1 = gA(1, 1);
    Fa2 = gA(2, 0); Fb2 = gA(2, 1);
    Fa3 = gA(3, 0); Fb3 = gA(3, 1);
    Fa4 = gA(4, 0); Fb4 = gA(4, 1);
    auto gB = [&](int T) {
      f32x4 r;
#pragma unroll
      for (int j = 0; j < 4; ++j) {
        int m = q * 4 + j;
        int row = rowmap(T, m);
        r[j] = gscale(T, m) * (bi[row] + bh[row]);
      }
      return r;
    };
    Bi = gB(0); Bf = gB(1); Bg = gB(2); Bo = gB(3); BL = gB(4);
  }

  // x prefetch (wave0): dwordx4 = pair block of 2 timesteps.
  // pair p floats 16p..16p+15: q0,q1 -> t=2p f0..7; q2,q3 -> t=2p+1 f0..7.
  // group j = pairs 4j..4j+3 (timesteps 8j..8j+7).
  const float* xb = x + (size_t)(blockIdx.x * 16 + n) * (T_LEN * 8) + 4 * q;
  f32x4 xA{}, xB{}, xC{}, xD{};
  if (w == 0) {
    xA = *(const f32x4*)(xb);        // pair 0
    xB = *(const f32x4*)(xb + 16);   // pair 1
    xC = *(const f32x4*)(xb + 32);   // pair 2
    xD = *(const f32x4*)(xb + 48);   // pair 3
  }

  // ---- main loop: 8 timesteps per barrier ----
#pragma unroll 1
  for (int j = 0; j <= NJ; ++j) {
    asm volatile("" ::: "memory");   // pin LDS traffic in-loop (R4 fix)
    __builtin_amdgcn_s_setprio(1);   // computing waves outrank barrier-parked
    const int wp = j & 1, rp = wp ^ 1;
    if (w == 0) {
      if (j <= 41) {
        // stage x group j: pair P -> row P, col-half (q>>1) (t even/odd)
        f16x4 xh;
        xh[0] = (f16)xA[0]; xh[1] = (f16)xA[1]; xh[2] = (f16)xA[2]; xh[3] = (f16)xA[3];
        *(f16x4*)&zT0[0][n * 64 + SWZ1(n, (q >> 1) * 32 + 4 * (q & 1))] = xh;
        xh[0] = (f16)xB[0]; xh[1] = (f16)xB[1]; xh[2] = (f16)xB[2]; xh[3] = (f16)xB[3];
        *(f16x4*)&zT0[1][n * 64 + SWZ1(n, (q >> 1) * 32 + 4 * (q & 1))] = xh;
        xh[0] = (f16)xC[0]; xh[1] = (f16)xC[1]; xh[2] = (f16)xC[2]; xh[3] = (f16)xC[3];
        *(f16x4*)&zT0[2][n * 64 + SWZ1(n, (q >> 1) * 32 + 4 * (q & 1))] = xh;
        xh[0] = (f16)xD[0]; xh[1] = (f16)xD[1]; xh[2] = (f16)xD[2]; xh[3] = (f16)xD[3];
        *(f16x4*)&zT0[3][n * 64 + SWZ1(n, (q >> 1) * 32 + 4 * (q & 1))] = xh;
        // prefetch group j+1 (one full iteration of slack)
        int g = (j + 1 > 41) ? 41 : j + 1;
        xA = *(const f32x4*)(xb + (size_t)(4 * g) * 16);
        xB = *(const f32x4*)(xb + (size_t)(4 * g + 1) * 16);
        xC = *(const f32x4*)(xb + (size_t)(4 * g + 2) * 16);
        xD = *(const f32x4*)(xb + (size_t)(4 * g + 3) * 16);
        f16* p1 = &zT1[wp][0][0];
        L0S(0, 0,  0, 32, p1 + 0 * 1024, 0)    // t=8j
        L0S(0, 32, 1, 0,  p1 + 0 * 1024, 32)   // t=8j+1
        L0S(1, 0,  1, 32, p1 + 1 * 1024, 0)    // t=8j+2
        L0S(1, 32, 2, 0,  p1 + 1 * 1024, 32)   // t=8j+3
        L0S(2, 0,  2, 32, p1 + 2 * 1024, 0)    // t=8j+4
        L0S(2, 32, 3, 0,  p1 + 2 * 1024, 32)   // t=8j+5
        L0S(3, 0,  3, 32, p1 + 3 * 1024, 0)    // t=8j+6
        L0S(3, 32, 0, 0,  p1 + 3 * 1024, 32)   // t=8j+7 (h0 -> row0 half0, next iter)
      }
    } else if (w == 1) {
      if (j >= 1 && j <= 42) {
        // L1 group j-1: h_in = h0 (published last iter), h_self in registers.
        // PRE/FIN pipeline: substep s+1's Fa-MFMAs fill substep s's bperm shadow.
        f16* s1 = &zT1[rp][0][0];
        f16x8 a0 = *(const f16x8*)&s1[0 * 1024 + n * 64 + SWZ1(n, 0  + q * 8)];
        f16x8 a1 = *(const f16x8*)&s1[0 * 1024 + n * 64 + SWZ1(n, 32 + q * 8)];
        f16x8 a2 = *(const f16x8*)&s1[1 * 1024 + n * 64 + SWZ1(n, 0  + q * 8)];
        f16x8 a3 = *(const f16x8*)&s1[1 * 1024 + n * 64 + SWZ1(n, 32 + q * 8)];
        f16x8 a4 = *(const f16x8*)&s1[2 * 1024 + n * 64 + SWZ1(n, 0  + q * 8)];
        f16x8 a5 = *(const f16x8*)&s1[2 * 1024 + n * 64 + SWZ1(n, 32 + q * 8)];
        f16x8 a6 = *(const f16x8*)&s1[3 * 1024 + n * 64 + SWZ1(n, 0  + q * 8)];
        f16x8 a7 = *(const f16x8*)&s1[3 * 1024 + n * 64 + SWZ1(n, 32 + q * 8)];
        f16* p2 = &zT2[wp][0][0];
        f32x4 tA0, tA1, tA2, tA3, tA4, tB0, tB1, tB2, tB3, tB4;
        f16x8 bb;
        PRE5(a0, tA0, tA1, tA2, tA3, tA4)
        BBGEN(bb) PRE5(a1, tB0, tB1, tB2, tB3, tB4) FIN5(bb, tA0, tA1, tA2, tA3, tA4, p2 + 0 * 1024, 0)
        BBGEN(bb) PRE5(a2, tA0, tA1, tA2, tA3, tA4) FIN5(bb, tB0, tB1, tB2, tB3, tB4, p2 + 0 * 1024, 32)
        BBGEN(bb) PRE5(a3, tB0, tB1, tB2, tB3, tB4) FIN5(bb, tA0, tA1, tA2, tA3, tA4, p2 + 1 * 1024, 0)
        BBGEN(bb) PRE5(a4, tA0, tA1, tA2, tA3, tA4) FIN5(bb, tB0, tB1, tB2, tB3, tB4, p2 + 1 * 1024, 32)
        BBGEN(bb) PRE5(a5, tB0, tB1, tB2, tB3, tB4) FIN5(bb, tA0, tA1, tA2, tA3, tA4, p2 + 2 * 1024, 0)
        BBGEN(bb) PRE5(a6, tA0, tA1, tA2, tA3, tA4) FIN5(bb, tB0, tB1, tB2, tB3, tB4, p2 + 2 * 1024, 32)
        BBGEN(bb) PRE5(a7, tB0, tB1, tB2, tB3, tB4) FIN5(bb, tA0, tA1, tA2, tA3, tA4, p2 + 3 * 1024, 0)
        BBGEN(bb)                                   FIN5(bb, tB0, tB1, tB2, tB3, tB4, p2 + 3 * 1024, 32)
      }
    } else {
      if (j >= 2) {
        // L2 group j-2: h_in = h1, h_self in registers; no publishes
        f16* s2 = &zT2[rp][0][0];
        f16x8 a0 = *(const f16x8*)&s2[0 * 1024 + n * 64 + SWZ1(n, 0  + q * 8)];
        f16x8 a1 = *(const f16x8*)&s2[0 * 1024 + n * 64 + SWZ1(n, 32 + q * 8)];
        f16x8 a2 = *(const f16x8*)&s2[1 * 1024 + n * 64 + SWZ1(n, 0  + q * 8)];
        f16x8 a3 = *(const f16x8*)&s2[1 * 1024 + n * 64 + SWZ1(n, 32 + q * 8)];
        f16x8 a4 = *(const f16x8*)&s2[2 * 1024 + n * 64 + SWZ1(n, 0  + q * 8)];
        f16x8 a5 = *(const f16x8*)&s2[2 * 1024 + n * 64 + SWZ1(n, 32 + q * 8)];
        f16x8 a6 = *(const f16x8*)&s2[3 * 1024 + n * 64 + SWZ1(n, 0  + q * 8)];
        f16x8 a7 = *(const f16x8*)&s2[3 * 1024 + n * 64 + SWZ1(n, 32 + q * 8)];
        f32x4 tA0, tA1, tA2, tA3, tA4, tB0, tB1, tB2, tB3, tB4;
        f16x8 bb;
        PRE5(a0, tA0, tA1, tA2, tA3, tA4)
        BBGEN(bb) PRE5(a1, tB0, tB1, tB2, tB3, tB4) FIN5(bb, tA0, tA1, tA2, tA3, tA4, (f16*)nullptr, 0)
        BBGEN(bb) PRE5(a2, tA0, tA1, tA2, tA3, tA4) FIN5(bb, tB0, tB1, tB2, tB3, tB4, (f16*)nullptr, 0)
        BBGEN(bb) PRE5(a3, tB0, tB1, tB2, tB3, tB4) FIN5(bb, tA0, tA1, tA2, tA3, tA4, (f16*)nullptr, 0)
        BBGEN(bb) PRE5(a4, tA0, tA1, tA2, tA3, tA4) FIN5(bb, tB0, tB1, tB2, tB3, tB4, (f16*)nullptr, 0)
        BBGEN(bb) PRE5(a5, tB0, tB1, tB2, tB3, tB4) FIN5(bb, tA0, tA1, tA2, tA3, tA4, (f16*)nullptr, 0)
        BBGEN(bb) PRE5(a6, tA0, tA1, tA2, tA3, tA4) FIN5(bb, tB0, tB1, tB2, tB3, tB4, (f16*)nullptr, 0)
        BBGEN(bb) PRE5(a7, tB0, tB1, tB2, tB3, tB4) FIN5(bb, tA0, tA1, tA2, tA3, tA4, (f16*)nullptr, 0)
        BBGEN(bb)                                   FIN5(bb, tB0, tB1, tB2, tB3, tB4, (f16*)nullptr, 0)
      }
    }
    __builtin_amdgcn_s_setprio(0);
    // LDS-only barrier: cross-wave handoff needs lgkmcnt(0), NOT vmcnt(0) —
    // wave0's in-flight x loads stay outstanding across it (R9 fix).
    asm volatile("s_waitcnt lgkmcnt(0)\n\ts_barrier" ::: "memory");
  }

  // ---- FC head (wave2): final h2(335) lives in hvS/hlS registers.
  if (w == 2) {
    // park h2 in LDS (c32..51 of zT2[1][0]) so each lane can read all 20 units
    *(f16x4*)&zT2[1][0][n * 64 + SWZ1(n, 32 + q * 4)] = hvS;
    zT2[1][0][n * 64 + SWZ1(n, 48 + q)] = hlS;
    asm volatile("s_waitcnt lgkmcnt(0)" ::: "memory");
    const f16* hb = &zT2[1][0][0];
    f16x4 hv0 = *(const f16x4*)&hb[n * 64 + SWZ1(n, 32)];
    f16x4 hv1 = *(const f16x4*)&hb[n * 64 + SWZ1(n, 36)];
    f16x4 hv2 = *(const f16x4*)&hb[n * 64 + SWZ1(n, 40)];
    f16x4 hv3 = *(const f16x4*)&hb[n * 64 + SWZ1(n, 44)];
    f16x4 hv4 = *(const f16x4*)&hb[n * 64 + SWZ1(n, 48)];
    float p = 0.f;
#pragma unroll
    for (int i = 0; i < 5; ++i) {
      int d = q * 5 + i;
      const float* wr = fc1w + d * 20;
      float s = fc1b[d]
        + wr[0]  * (float)hv0[0] + wr[1]  * (float)hv0[1] + wr[2]  * (float)hv0[2] + wr[3]  * (float)hv0[3]
        + wr[4]  * (float)hv1[0] + wr[5]  * (float)hv1[1] + wr[6]  * (float)hv1[2] + wr[7]  * (float)hv1[3]
        + wr[8]  * (float)hv2[0] + wr[9]  * (float)hv2[1] + wr[10] * (float)hv2[2] + wr[11] * (float)hv2[3]
        + wr[12] * (float)hv3[0] + wr[13] * (float)hv3[1] + wr[14] * (float)hv3[2] + wr[15] * (float)hv3[3]
        + wr[16] * (float)hv4[0] + wr[17] * (float)hv4[1] + wr[18] * (float)hv4[2] + wr[19] * (float)hv4[3];
      p += fc2w[d] * fmaxf(s, 0.f);
    }
    pbuf[n * 4 + q] = p;            // wave-internal, in-order
    if (q == 0) {
      f32x4 pv = *(const f32x4*)&pbuf[n * 4];
      out[blockIdx.x * 16 + n] = pv[0] + pv[1] + pv[2] + pv[3] + fc2b[0];
    }
  }
}

extern "C" void kernel_launch(void* const* d_in, const int* in_sizes, int n_in,
                              void* d_out, int out_size, void* d_ws, size_t ws_size,
                              hipStream_t stream) {
  const float* x    = (const float*)d_in[0];
  const float* Wih0 = (const float*)d_in[1];
  const float* Whh0 = (const float*)d_in[2];
  const float* bih0 = (const float*)d_in[3];
  const float* bhh0 = (const float*)d_in[4];
  const float* Wih1 = (const float*)d_in[5];
  const float* Whh1 = (const float*)d_in[6];
  const float* bih1 = (const float*)d_in[7];
  const float* bhh1 = (const float*)d_in[8];
  const float* Wih2 = (const float*)d_in[9];
  const float* Whh2 = (const float*)d_in[10];
  const float* bih2 = (const float*)d_in[11];
  const float* bhh2 = (const float*)d_in[12];
  const float* fc1w = (const float*)d_in[13];
  const float* fc1b = (const float*)d_in[14];
  const float* fc2w = (const float*)d_in[15];
  const float* fc2b = (const float*)d_in[16];
  float* out = (float*)d_out;

  hipLaunchKernelGGL(lstm3_ws_kernel, dim3(8192 / 16), dim3(192), 0, stream,
                     x, Wih0, Whh0, bih0, bhh0,
                     Wih1, Whh1, bih1, bhh1,
                     Wih2, Whh2, bih2, bhh2,
                     fc1w, fc1b, fc2w, fc2b, out);
}

// Round 11
// 380.437 us; speedup vs baseline: 1.0029x; 1.0029x over previous
//
#include <hip/hip_runtime.h>

// 3-layer LSTM (B=8192, T=336, F=8, H=20) + FC(20->20 relu) + FC(20->1).
//
// Round 17: DS-FREE RECURRENCE. The per-substep critical chain was
// hvS -> 7 DS ops (bperm/swizzle) -> bb -> MFMA -> cells -> hvS; the DS hop
// (~40-120cy) existed only because D-layout h (4+1 units/lane) mismatches
// the K=32 B-layout (8/lane). Fix: legacy v_mfma_f32_16x16x16_f16 has
// B[k][n]: k=4q+j -> lane(n,q) holds h[4q..4q+3] = hvS VERBATIM.
//  - h_self main (k=0..15): B = hvS directly, A = Whh cols 0..15.
//  - h_self leftover (u=16..19): A[m][4q+j] = (j==0)?Whh[m][16+q]:0,
//    B = splat4(hlS) (lane-local). sum_q W[m][16+q]*h[16+q]. No lane moves.
//  - L0's x path: same trick. A-weights Xe (k=0..7 = even-ts features) /
//    Xo (k=8..15 = odd-ts features) consume the dwordx4 x-prefetch regs
//    DIRECTLY (q0/q1 hold even-ts f0..7, q2/q3 odd-ts f0..7). zT0 DELETED.
//  Chain now: 2 chained MFMA + cell trans (~150cy vs ~280). ZERO DS on any
//  recurrence path. BBGEN/bperm/swizzle deleted. 16x16x16 D-layout == the
//  16x16x32 D-layout (4 regs, m=4q+r), so accumulators compose across both.
//  Kept: 8 ts/barrier (R14), prescaled gates (R12), hoisted h_in reads +
//  setprio (R11), lgkm-only barrier (R9), XOR swizzle on zT1/zT2 (R9),
//  unit-major leftover cells (R10), LICM pin (R4).
//
// MFMA layouts (m89/m120-verified): 16x16x32: A[m][k]: m=lane&15,
// k=(lane>>4)*8+j; 16x16x16: k=(lane>>4)*4+j; D (both): n=lane&15,
// m=(lane>>4)*4+reg.

#define T_LEN 336
#define NJ 43   // j=0..43; w0: group j (t=8j..8j+7, j<=41); w1: group j-1; w2: group j-2

typedef _Float16 f16;
typedef _Float16 f16x4 __attribute__((ext_vector_type(4)));
typedef _Float16 f16x8 __attribute__((ext_vector_type(8)));
typedef float f32x4 __attribute__((ext_vector_type(4)));

#define MFMA(a, b, c) __builtin_amdgcn_mfma_f32_16x16x32_f16((a), (b), (c), 0, 0, 0)
#define M16(a, b, c)  __builtin_amdgcn_mfma_f32_16x16x16f16((a), (b), (c), 0, 0, 0)

// 16B-slot XOR swizzle for 64-f16 (128B) rows
#define SWZ1(n, c) ((c) ^ (((n) & 7) << 3))

#define KS1 1.4426950408889634f   // log2(e)
#define KS2 2.8853900817779268f   // 2*log2(e)

// prescaled activations: y arrives as -KS1*x (sigm) / -KS2*x (tanh)
__device__ __forceinline__ float sigm_p(float y) {
  return __builtin_amdgcn_rcpf(1.0f + __builtin_amdgcn_exp2f(y));
}
__device__ __forceinline__ float tanh_p(float y) {
  return 2.0f * __builtin_amdgcn_rcpf(1.0f + __builtin_amdgcn_exp2f(y)) - 1.0f;
}
__device__ __forceinline__ float tanh_fast(float x) {   // raw arg (cell state)
  return 2.0f * __builtin_amdgcn_rcpf(1.0f + __builtin_amdgcn_exp2f(-KS2 * x)) - 1.0f;
}

// 5 in-lane cells; gate inputs arrive PRESCALED (see loaders).
#define CELLS5(DI, DF, DG, DO, DL, HV, HL) {                                                \
  { float i_=sigm_p((DI)[0]), f_=sigm_p((DF)[0]), g_=tanh_p((DG)[0]), o_=sigm_p((DO)[0]);   \
    c0 = f_*c0 + i_*g_; (HV)[0] = (f16)(o_*tanh_fast(c0)); }                                \
  { float i_=sigm_p((DI)[1]), f_=sigm_p((DF)[1]), g_=tanh_p((DG)[1]), o_=sigm_p((DO)[1]);   \
    c1 = f_*c1 + i_*g_; (HV)[1] = (f16)(o_*tanh_fast(c1)); }                                \
  { float i_=sigm_p((DI)[2]), f_=sigm_p((DF)[2]), g_=tanh_p((DG)[2]), o_=sigm_p((DO)[2]);   \
    c2 = f_*c2 + i_*g_; (HV)[2] = (f16)(o_*tanh_fast(c2)); }                                \
  { float i_=sigm_p((DI)[3]), f_=sigm_p((DF)[3]), g_=tanh_p((DG)[3]), o_=sigm_p((DO)[3]);   \
    c3 = f_*c3 + i_*g_; (HV)[3] = (f16)(o_*tanh_fast(c3)); }                                \
  { float i_=sigm_p((DL)[0]), f_=sigm_p((DL)[1]), g_=tanh_p((DL)[2]), o_=sigm_p((DL)[3]);   \
    cL = f_*cL + i_*g_; (HL) = (f16)(o_*tanh_fast(cL)); } }

// recurrent fold: bm = hvS (K=16 B-frag, h[4q..4q+3] in-lane);
// bl = splat(hlS) (k=16..19 via j==0-masked Hl weights).
#define HFOLD(T0, T1, T2, T3, T4, DI, DF, DG, DN, DL) {                                     \
  f16x4 bm = hvS;                                                                           \
  f16x4 bl; bl[0] = hlS; bl[1] = hlS; bl[2] = hlS; bl[3] = hlS;                             \
  DI = M16(Hl0, bl, M16(Hm0, bm, T0));                                                      \
  DF = M16(Hl1, bl, M16(Hm1, bm, T1));                                                      \
  DG = M16(Hl2, bl, M16(Hm2, bm, T2));                                                      \
  DN = M16(Hl3, bl, M16(Hm3, bm, T3));                                                      \
  DL = M16(Hl4, bl, M16(Hm4, bm, T4)); }

#define PUBLISH(PUBP, PC, HV, HL) {                                                         \
  f16* dp_ = (PUBP);                                                                        \
  if (dp_) { *(f16x4*)&dp_[n * 64 + SWZ1(n, (PC) + q * 4)] = (HV);                          \
             dp_[n * 64 + SWZ1(n, (PC) + 16 + q)] = (HL); } }

// L0 substep: x via XP (Xe even-ts / Xo odd-ts weights) consuming frag XF
// directly from the prefetch regs; h0 recurrence in-register via HFOLD.
#define L0R(XP, XF, PUBP, PC) {                                                             \
  f32x4 t0 = M16(XP##0, (XF), Bi), t1 = M16(XP##1, (XF), Bf),                               \
        t2 = M16(XP##2, (XF), Bg), t3 = M16(XP##3, (XF), Bo),                               \
        t4 = M16(XP##4, (XF), BL);                                                          \
  f32x4 di, df, dg, dn, dl;                                                                 \
  HFOLD(t0, t1, t2, t3, t4, di, df, dg, dn, dl)                                             \
  f16x4 hv; f16 hl; CELLS5(di, df, dg, dn, dl, hv, hl)                                      \
  hvS = hv; hlS = hl;                                                                       \
  PUBLISH(PUBP, PC, hv, hl) }

// L1/L2 substep: h_in via K=32 MFMA (LDS, off-chain); h_self via HFOLD.
#define MSTEP_R(BA, PUBP, PC) {                                                             \
  f32x4 t0 = MFMA(Fa0, (BA), Bi), t1 = MFMA(Fa1, (BA), Bf),                                 \
        t2 = MFMA(Fa2, (BA), Bg), t3 = MFMA(Fa3, (BA), Bo),                                 \
        t4 = MFMA(Fa4, (BA), BL);                                                           \
  f32x4 di, df, dg, dn, dl;                                                                 \
  HFOLD(t0, t1, t2, t3, t4, di, df, dg, dn, dl)                                             \
  f16x4 hv; f16 hl; CELLS5(di, df, dg, dn, dl, hv, hl)                                      \
  hvS = hv; hlS = hl;                                                                       \
  PUBLISH(PUBP, PC, hv, hl) }

__global__ __launch_bounds__(192, 2) void lstm3_ws_kernel(
    const float* __restrict__ x,
    const float* __restrict__ Wih0, const float* __restrict__ Whh0,
    const float* __restrict__ bih0, const float* __restrict__ bhh0,
    const float* __restrict__ Wih1, const float* __restrict__ Whh1,
    const float* __restrict__ bih1, const float* __restrict__ bhh1,
    const float* __restrict__ Wih2, const float* __restrict__ Whh2,
    const float* __restrict__ bih2, const float* __restrict__ bhh2,
    const float* __restrict__ fc1w, const float* __restrict__ fc1b,
    const float* __restrict__ fc2w, const float* __restrict__ fc2b,
    float* __restrict__ out)
{
  // [parity][rowset r]: substeps 2r (cols 0..) and 2r+1 (cols 32..)
  __shared__ __align__(16) f16 zT1[2][4][1024];
  __shared__ __align__(16) f16 zT2[2][4][1024];
  __shared__ __align__(16) float pbuf[64];          // fc2 partials

  const int tid  = threadIdx.x;
  const int w    = tid >> 6;        // wave id = layer id
  const int lane = tid & 63;
  const int n = lane & 15;          // batch elem (N index)
  const int q = lane >> 4;          // quad

  // ---- zero z buffers (h(.)=0, c implicit 0, pads 0) ----
  {
    f16x8 zer;
#pragma unroll
    for (int j = 0; j < 8; ++j) zer[j] = (f16)0.f;
    for (int i = tid; i < 1024; i += 192) ((f16x8*)&zT1[0][0][0])[i] = zer;
    for (int i = tid; i < 1024; i += 192) ((f16x8*)&zT2[0][0][0])[i] = zer;
  }
  __syncthreads();

  // ---- per-wave register-resident fragments (PRESCALED) ----
  auto rowmap = [](int T, int m) { return T < 4 ? T * 20 + m : (m & 3) * 20 + 16 + (m >> 2); };
  auto gscale = [](int T, int m) {
    int g = (T < 4) ? T : (m & 3);
    return (g == 2) ? -KS2 : -KS1;
  };

  const float* WiP = (w == 0) ? Wih0 : (w == 1) ? Wih1 : Wih2;
  const float* WhP = (w == 0) ? Whh0 : (w == 1) ? Whh1 : Whh2;
  const float* biP = (w == 0) ? bih0 : (w == 1) ? bih1 : bih2;
  const float* bhP = (w == 0) ? bhh0 : (w == 1) ? bhh1 : bhh2;

  f16x8 Fa0{}, Fa1{}, Fa2{}, Fa3{}, Fa4{};   // w1/w2: K=32 h_in frags
  f16x4 Xe0{}, Xe1{}, Xe2{}, Xe3{}, Xe4{};   // w0: x weights, even-ts slots
  f16x4 Xo0{}, Xo1{}, Xo2{}, Xo3{}, Xo4{};   // w0: x weights, odd-ts slots
  f16x4 Hm0{}, Hm1{}, Hm2{}, Hm3{}, Hm4{};   // h_self main (k=0..15)
  f16x4 Hl0{}, Hl1{}, Hl2{}, Hl3{}, Hl4{};   // h_self leftover (u=16+q, j==0)
  f32x4 Bi{}, Bf{}, Bg{}, Bo{}, BL{};
  float c0 = 0.f, c1 = 0.f, c2 = 0.f, c3 = 0.f, cL = 0.f;
  f16x4 hvS{};                     // register h_self state (all waves now)
  f16 hlS = (f16)0.f;

  {
    // h_self weights (all waves, from own Whh)
    auto gM = [&](int T) {
      int row = rowmap(T, n);
      float sc = gscale(T, n);
      f16x4 r;
#pragma unroll
      for (int j = 0; j < 4; ++j) r[j] = (f16)(sc * WhP[row * 20 + q * 4 + j]);
      return r;
    };
    auto gL = [&](int T) {
      int row = rowmap(T, n);
      float sc = gscale(T, n);
      f16x4 r;
      r[0] = (f16)(sc * WhP[row * 20 + 16 + q]);
      r[1] = (f16)0.f; r[2] = (f16)0.f; r[3] = (f16)0.f;
      return r;
    };
    Hm0 = gM(0); Hm1 = gM(1); Hm2 = gM(2); Hm3 = gM(3); Hm4 = gM(4);
    Hl0 = gL(0); Hl1 = gL(1); Hl2 = gL(2); Hl3 = gL(3); Hl4 = gL(4);
    auto gB = [&](int T) {
      f32x4 r;
#pragma unroll
      for (int j = 0; j < 4; ++j) {
        int m = q * 4 + j;
        int row = rowmap(T, m);
        r[j] = gscale(T, m) * (biP[row] + bhP[row]);
      }
      return r;
    };
    Bi = gB(0); Bf = gB(1); Bg = gB(2); Bo = gB(3); BL = gB(4);
  }

  if (w == 0) {
    // x weights: even-ts features in k=0..7, odd-ts features in k=8..15
    auto gXE = [&](int T) {
      int row = rowmap(T, n);
      float sc = gscale(T, n);
      f16x4 r;
#pragma unroll
      for (int j = 0; j < 4; ++j) {
        int k = q * 4 + j;
        r[j] = (f16)((k < 8) ? sc * WiP[row * 8 + k] : 0.f);
      }
      return r;
    };
    auto gXO = [&](int T) {
      int row = rowmap(T, n);
      float sc = gscale(T, n);
      f16x4 r;
#pragma unroll
      for (int j = 0; j < 4; ++j) {
        int k = q * 4 + j;
        r[j] = (f16)((k >= 8) ? sc * WiP[row * 8 + k - 8] : 0.f);
      }
      return r;
    };
    Xe0 = gXE(0); Xe1 = gXE(1); Xe2 = gXE(2); Xe3 = gXE(3); Xe4 = gXE(4);
    Xo0 = gXO(0); Xo1 = gXO(1); Xo2 = gXO(2); Xo3 = gXO(3); Xo4 = gXO(4);
  } else {
    // h_in frags: K=32 chunk = [h_in 20 | 0 pad]
    auto gA = [&](int T) {
      int row = rowmap(T, n);
      float sc = gscale(T, n);
      f16x8 r;
#pragma unroll
      for (int j = 0; j < 8; ++j) {
        int k = q * 8 + j;
        r[j] = (f16)((k < 20) ? sc * WiP[row * 20 + k] : 0.f);
      }
      return r;
    };
    Fa0 = gA(0); Fa1 = gA(1); Fa2 = gA(2); Fa3 = gA(3); Fa4 = gA(4);
  }

  // x prefetch (wave0): dwordx4 = pair block of 2 timesteps.
  // pair p floats 16p..16p+15: q0,q1 -> t=2p f0..7; q2,q3 -> t=2p+1 f0..7.
  // This q-mapping IS the 16x16x16 B-slot mapping (k=4q+j) for Xe/Xo.
  const float* xb = x + (size_t)(blockIdx.x * 16 + n) * (T_LEN * 8) + 4 * q;
  f32x4 xA{}, xB{}, xC{}, xD{};
  if (w == 0) {
    xA = *(const f32x4*)(xb);        // pair 0
    xB = *(const f32x4*)(xb + 16);   // pair 1
    xC = *(const f32x4*)(xb + 32);   // pair 2
    xD = *(const f32x4*)(xb + 48);   // pair 3
  }

  // ---- main loop: 8 timesteps per barrier ----
#pragma unroll 1
  for (int j = 0; j <= NJ; ++j) {
    asm volatile("" ::: "memory");   // pin LDS traffic in-loop (R4 fix)
    __builtin_amdgcn_s_setprio(1);   // computing waves outrank barrier-parked
    const int wp = j & 1, rp = wp ^ 1;
    if (w == 0) {
      if (j <= 41) {
        // convert current group's 4 pairs to f16 B-frags, then prefetch j+1
        f16x4 xf0, xf1, xf2, xf3;
        xf0[0] = (f16)xA[0]; xf0[1] = (f16)xA[1]; xf0[2] = (f16)xA[2]; xf0[3] = (f16)xA[3];
        xf1[0] = (f16)xB[0]; xf1[1] = (f16)xB[1]; xf1[2] = (f16)xB[2]; xf1[3] = (f16)xB[3];
        xf2[0] = (f16)xC[0]; xf2[1] = (f16)xC[1]; xf2[2] = (f16)xC[2]; xf2[3] = (f16)xC[3];
        xf3[0] = (f16)xD[0]; xf3[1] = (f16)xD[1]; xf3[2] = (f16)xD[2]; xf3[3] = (f16)xD[3];
        int g = (j + 1 > 41) ? 41 : j + 1;
        xA = *(const f32x4*)(xb + (size_t)(4 * g) * 16);
        xB = *(const f32x4*)(xb + (size_t)(4 * g + 1) * 16);
        xC = *(const f32x4*)(xb + (size_t)(4 * g + 2) * 16);
        xD = *(const f32x4*)(xb + (size_t)(4 * g + 3) * 16);
        f16* p1 = &zT1[wp][0][0];
        L0R(Xe, xf0, p1 + 0 * 1024, 0)    // t=8j
        L0R(Xo, xf0, p1 + 0 * 1024, 32)   // t=8j+1
        L0R(Xe, xf1, p1 + 1 * 1024, 0)    // t=8j+2
        L0R(Xo, xf1, p1 + 1 * 1024, 32)   // t=8j+3
        L0R(Xe, xf2, p1 + 2 * 1024, 0)    // t=8j+4
        L0R(Xo, xf2, p1 + 2 * 1024, 32)   // t=8j+5
        L0R(Xe, xf3, p1 + 3 * 1024, 0)    // t=8j+6
        L0R(Xo, xf3, p1 + 3 * 1024, 32)   // t=8j+7
      }
    } else if (w == 1) {
      if (j >= 1 && j <= 42) {
        // L1 group j-1: h_in = h0 (published last iter, hoisted off-chain)
        f16* s1 = &zT1[rp][0][0];
        f16x8 a0 = *(const f16x8*)&s1[0 * 1024 + n * 64 + SWZ1(n, 0  + q * 8)];
        f16x8 a1 = *(const f16x8*)&s1[0 * 1024 + n * 64 + SWZ1(n, 32 + q * 8)];
        f16x8 a2 = *(const f16x8*)&s1[1 * 1024 + n * 64 + SWZ1(n, 0  + q * 8)];
        f16x8 a3 = *(const f16x8*)&s1[1 * 1024 + n * 64 + SWZ1(n, 32 + q * 8)];
        f16x8 a4 = *(const f16x8*)&s1[2 * 1024 + n * 64 + SWZ1(n, 0  + q * 8)];
        f16x8 a5 = *(const f16x8*)&s1[2 * 1024 + n * 64 + SWZ1(n, 32 + q * 8)];
        f16x8 a6 = *(const f16x8*)&s1[3 * 1024 + n * 64 + SWZ1(n, 0  + q * 8)];
        f16x8 a7 = *(const f16x8*)&s1[3 * 1024 + n * 64 + SWZ1(n, 32 + q * 8)];
        f16* p2 = &zT2[wp][0][0];
        MSTEP_R(a0, p2 + 0 * 1024, 0)
        MSTEP_R(a1, p2 + 0 * 1024, 32)
        MSTEP_R(a2, p2 + 1 * 1024, 0)
        MSTEP_R(a3, p2 + 1 * 1024, 32)
        MSTEP_R(a4, p2 + 2 * 1024, 0)
        MSTEP_R(a5, p2 + 2 * 1024, 32)
        MSTEP_R(a6, p2 + 3 * 1024, 0)
        MSTEP_R(a7, p2 + 3 * 1024, 32)
      }
    } else {
      if (j >= 2) {
        // L2 group j-2: h_in = h1; no publishes
        f16* s2 = &zT2[rp][0][0];
        f16x8 a0 = *(const f16x8*)&s2[0 * 1024 + n * 64 + SWZ1(n, 0  + q * 8)];
        f16x8 a1 = *(const f16x8*)&s2[0 * 1024 + n * 64 + SWZ1(n, 32 + q * 8)];
        f16x8 a2 = *(const f16x8*)&s2[1 * 1024 + n * 64 + SWZ1(n, 0  + q * 8)];
        f16x8 a3 = *(const f16x8*)&s2[1 * 1024 + n * 64 + SWZ1(n, 32 + q * 8)];
        f16x8 a4 = *(const f16x8*)&s2[2 * 1024 + n * 64 + SWZ1(n, 0  + q * 8)];
        f16x8 a5 = *(const f16x8*)&s2[2 * 1024 + n * 64 + SWZ1(n, 32 + q * 8)];
        f16x8 a6 = *(const f16x8*)&s2[3 * 1024 + n * 64 + SWZ1(n, 0  + q * 8)];
        f16x8 a7 = *(const f16x8*)&s2[3 * 1024 + n * 64 + SWZ1(n, 32 + q * 8)];
        MSTEP_R(a0, (f16*)nullptr, 0)
        MSTEP_R(a1, (f16*)nullptr, 0)
        MSTEP_R(a2, (f16*)nullptr, 0)
        MSTEP_R(a3, (f16*)nullptr, 0)
        MSTEP_R(a4, (f16*)nullptr, 0)
        MSTEP_R(a5, (f16*)nullptr, 0)
        MSTEP_R(a6, (f16*)nullptr, 0)
        MSTEP_R(a7, (f16*)nullptr, 0)
      }
    }
    __builtin_amdgcn_s_setprio(0);
    // LDS-only barrier: cross-wave handoff needs lgkmcnt(0), NOT vmcnt(0) —
    // wave0's in-flight x loads stay outstanding across it (R9 fix).
    asm volatile("s_waitcnt lgkmcnt(0)\n\ts_barrier" ::: "memory");
  }

  // ---- FC head (wave2): final h2(335) lives in hvS/hlS registers.
  if (w == 2) {
    // park h2 in LDS (c32..51 of zT2[1][0]) so each lane can read all 20 units
    *(f16x4*)&zT2[1][0][n * 64 + SWZ1(n, 32 + q * 4)] = hvS;
    zT2[1][0][n * 64 + SWZ1(n, 48 + q)] = hlS;
    asm volatile("s_waitcnt lgkmcnt(0)" ::: "memory");
    const f16* hb = &zT2[1][0][0];
    f16x4 hv0 = *(const f16x4*)&hb[n * 64 + SWZ1(n, 32)];
    f16x4 hv1 = *(const f16x4*)&hb[n * 64 + SWZ1(n, 36)];
    f16x4 hv2 = *(const f16x4*)&hb[n * 64 + SWZ1(n, 40)];
    f16x4 hv3 = *(const f16x4*)&hb[n * 64 + SWZ1(n, 44)];
    f16x4 hv4 = *(const f16x4*)&hb[n * 64 + SWZ1(n, 48)];
    float p = 0.f;
#pragma unroll
    for (int i = 0; i < 5; ++i) {
      int d = q * 5 + i;
      const float* wr = fc1w + d * 20;
      float s = fc1b[d]
        + wr[0]  * (float)hv0[0] + wr[1]  * (float)hv0[1] + wr[2]  * (float)hv0[2] + wr[3]  * (float)hv0[3]
        + wr[4]  * (float)hv1[0] + wr[5]  * (float)hv1[1] + wr[6]  * (float)hv1[2] + wr[7]  * (float)hv1[3]
        + wr[8]  * (float)hv2[0] + wr[9]  * (float)hv2[1] + wr[10] * (float)hv2[2] + wr[11] * (float)hv2[3]
        + wr[12] * (float)hv3[0] + wr[13] * (float)hv3[1] + wr[14] * (float)hv3[2] + wr[15] * (float)hv3[3]
        + wr[16] * (float)hv4[0] + wr[17] * (float)hv4[1] + wr[18] * (float)hv4[2] + wr[19] * (float)hv4[3];
      p += fc2w[d] * fmaxf(s, 0.f);
    }
    pbuf[n * 4 + q] = p;            // wave-internal, in-order
    if (q == 0) {
      f32x4 pv = *(const f32x4*)&pbuf[n * 4];
      out[blockIdx.x * 16 + n] = pv[0] + pv[1] + pv[2] + pv[3] + fc2b[0];
    }
  }
}

extern "C" void kernel_launch(void* const* d_in, const int* in_sizes, int n_in,
                              void* d_out, int out_size, void* d_ws, size_t ws_size,
                              hipStream_t stream) {
  const float* x    = (const float*)d_in[0];
  const float* Wih0 = (const float*)d_in[1];
  const float* Whh0 = (const float*)d_in[2];
  const float* bih0 = (const float*)d_in[3];
  const float* bhh0 = (const float*)d_in[4];
  const float* Wih1 = (const float*)d_in[5];
  const float* Whh1 = (const float*)d_in[6];
  const float* bih1 = (const float*)d_in[7];
  const float* bhh1 = (const float*)d_in[8];
  const float* Wih2 = (const float*)d_in[9];
  const float* Whh2 = (const float*)d_in[10];
  const float* bih2 = (const float*)d_in[11];
  const float* bhh2 = (const float*)d_in[12];
  const float* fc1w = (const float*)d_in[13];
  const float* fc1b = (const float*)d_in[14];
  const float* fc2w = (const float*)d_in[15];
  const float* fc2b = (const float*)d_in[16];
  float* out = (float*)d_out;

  hipLaunchKernelGGL(lstm3_ws_kernel, dim3(8192 / 16), dim3(192), 0, stream,
                     x, Wih0, Whh0, bih0, bhh0,
                     Wih1, Whh1, bih1, bhh1,
                     Wih2, Whh2, bih2, bhh2,
                     fc1w, fc1b, fc2w, fc2b, out);
}